// Round 3
// baseline (702.611 us; speedup 1.0000x reference)
//
#include <hip/hip_runtime.h>
#include <math.h>

// Problem constants (from reference setup_inputs)
#define BB 256
#define NN 1024
#define DD 256
#define NWAVES 16
#define THREADS (NWAVES * 64)     // 1024
#define PPW (NN / NWAVES)         // 64 points per wave
#define CACHE_WAVES 2             // waves 0..1 keep their points in LDS
#define CACHEP (CACHE_WAVES * PPW)// 128 cached points = 128 KB
#define N_ITERS_C 10
#define LR_C 0.5f
#define EPS_C 1e-7f

__device__ __forceinline__ float wsum64(float v) {
    #pragma unroll
    for (int off = 32; off; off >>= 1) v += __shfl_xor(v, off, 64);
    return v;
}

// One workgroup per batch b. 16 waves x 64 lanes. Lane l of every wave owns
// dims [4l,4l+4) of D=256; each wave holds a replicated copy of the mean p.
// Each wave processes 64 of the 1024 points per pass. Waves 0-1 cache their
// 128 points in LDS after the first (init) pass; later passes read LDS, which
// shrinks the per-pass global stream to 224 MB (< 256 MiB Infinity Cache).
// LDS budget: 128KB cache + 16KB waveAcc + 4KB weights + 64B = ~148 KB.
__global__ __launch_bounds__(THREADS, 1)
void frechet_mean_kernel(const float* __restrict__ points,
                         const float* __restrict__ weights,
                         float* __restrict__ out) {
    const int b = blockIdx.x;
    const int w = threadIdx.x >> 6;
    const int lane = threadIdx.x & 63;
    const int lane4 = lane * 4;

    __shared__ float cacheQ[CACHEP][DD];   // 128 KB
    __shared__ float waveAcc[NWAVES][DD];  // 16 KB: per-wave grad partials
    __shared__ float wLds[NN];             // 4 KB: weights
    __shared__ float waveS[NWAVES];        // per-wave scalar partials

    const float* __restrict__ Qb = points + (size_t)b * NN * DD;
    const float* __restrict__ Wb = weights + (size_t)b * NN;
    const float* rowBase = Qb + (size_t)(w * PPW) * DD + lane4;

    // ---- stage weights once (reused 11x) ----
    wLds[threadIdx.x] = Wb[threadIdx.x];
    __syncthreads();

    // ---- init pass: acc = sum_n w_n q_n ; also populate LDS point cache ----
    float ax = 0.f, ay = 0.f, az = 0.f, aww = 0.f, swt = 0.f;
    #pragma unroll 4
    for (int i = 0; i < PPW; ++i) {
        const float4 q = *(const float4*)(rowBase + (size_t)i * DD);
        if (w < CACHE_WAVES)
            *(float4*)(&cacheQ[w * PPW + i][lane4]) = q;
        const float wt = wLds[w * PPW + i];
        ax = fmaf(wt, q.x, ax);
        ay = fmaf(wt, q.y, ay);
        az = fmaf(wt, q.z, az);
        aww = fmaf(wt, q.w, aww);
        swt += wt;
    }
    *(float4*)(&waveAcc[w][lane4]) = make_float4(ax, ay, az, aww);
    if (lane == 0) waveS[w] = swt;
    __syncthreads();

    float gx = 0.f, gy = 0.f, gz = 0.f, gw = 0.f, wsumTot = 0.f;
    #pragma unroll
    for (int j = 0; j < NWAVES; ++j) {
        const float4 t = *(const float4*)(&waveAcc[j][lane4]);
        gx += t.x; gy += t.y; gz += t.z; gw += t.w;
        wsumTot += waveS[j];
    }
    const float wsumInv = 1.0f / wsumTot;
    gx *= wsumInv; gy *= wsumInv; gz *= wsumInv; gw *= wsumInv;

    // p = g / max(||g||, eps)
    const float nrm2 = wsum64(gx * gx + gy * gy + gz * gz + gw * gw);
    const float rn = 1.0f / fmaxf(sqrtf(nrm2), EPS_C);
    float px = gx * rn, py = gy * rn, pz = gz * rn, pw = gw * rn;
    float pp = wsum64(px * px + py * py + pz * pz + pw * pw);  // ||p||^2

    const float CLIP = 1.0f - 1e-7f;  // jnp clip bounds in fp32

    for (int it = 0; it < N_ITERS_C; ++it) {
        __syncthreads();  // previous waveAcc reads done before rewrite
        float accx = 0.f, accy = 0.f, accz = 0.f, accw = 0.f, s = 0.f;

        // Two points per call, butterflies interleaved -> 2-deep ILP on the
        // shuffle chain (its dependent latency is the per-point critical
        // path). q stays in registers for both the dot and the rank-1
        // accumulation. ||u||^2 = 1 - 2 cos <p,q> + cos^2 ||p||^2 (inputs
        // are unit vectors; fp deviation ~1e-7, data has theta ~ pi/2).
        auto process2 = [&](const float4 q0, const float wc0,
                            const float4 q1, const float wc1) {
            float d0 = fmaf(q0.x, px, fmaf(q0.y, py, fmaf(q0.z, pz, q0.w * pw)));
            float d1 = fmaf(q1.x, px, fmaf(q1.y, py, fmaf(q1.z, pz, q1.w * pw)));
            #pragma unroll
            for (int off = 32; off; off >>= 1) {
                d0 += __shfl_xor(d0, off, 64);
                d1 += __shfl_xor(d1, off, 64);
            }
            const float c0v = fminf(fmaxf(d0, -CLIP), CLIP);
            const float c1v = fminf(fmaxf(d1, -CLIP), CLIP);
            const float th0 = acosf(c0v);
            const float th1 = acosf(c1v);
            float u0 = fmaf(c0v * c0v, pp, fmaf(-2.0f * c0v, d0, 1.0f));
            float u1 = fmaf(c1v * c1v, pp, fmaf(-2.0f * c1v, d1, 1.0f));
            const float c0 = wc0 * th0 * rsqrtf(fmaxf(u0, 1e-14f));
            const float c1 = wc1 * th1 * rsqrtf(fmaxf(u1, 1e-14f));
            accx = fmaf(c0, q0.x, fmaf(c1, q1.x, accx));
            accy = fmaf(c0, q0.y, fmaf(c1, q1.y, accy));
            accz = fmaf(c0, q0.z, fmaf(c1, q1.z, accz));
            accw = fmaf(c0, q0.w, fmaf(c1, q1.w, accw));
            s = fmaf(c0, c0v, fmaf(c1, c1v, s));
        };

        if (w < CACHE_WAVES) {
            #pragma unroll 2
            for (int i = 0; i < PPW; i += 2) {
                const float4 q0 = *(const float4*)(&cacheQ[w * PPW + i][lane4]);
                const float4 q1 = *(const float4*)(&cacheQ[w * PPW + i + 1][lane4]);
                process2(q0, wLds[w * PPW + i], q1, wLds[w * PPW + i + 1]);
            }
        } else {
            #pragma unroll 2
            for (int i = 0; i < PPW; i += 2) {
                const float4 q0 = *(const float4*)(rowBase + (size_t)i * DD);
                const float4 q1 = *(const float4*)(rowBase + (size_t)(i + 1) * DD);
                process2(q0, wLds[w * PPW + i], q1, wLds[w * PPW + i + 1]);
            }
        }

        *(float4*)(&waveAcc[w][lane4]) = make_float4(accx, accy, accz, accw);
        if (lane == 0) waveS[w] = s;
        __syncthreads();

        float grx = 0.f, gry = 0.f, grz = 0.f, grw = 0.f, sTot = 0.f;
        #pragma unroll
        for (int j = 0; j < NWAVES; ++j) {
            const float4 t = *(const float4*)(&waveAcc[j][lane4]);
            grx += t.x; gry += t.y; grz += t.z; grw += t.w;
            sTot += waveS[j];
        }
        // v = LR * wsumInv * (gr - sTot * p)
        const float scale = LR_C * wsumInv;
        const float vx = scale * (grx - sTot * px);
        const float vy = scale * (gry - sTot * py);
        const float vz = scale * (grz - sTot * pz);
        const float vw = scale * (grw - sTot * pw);

        const float t2 = wsum64(vx * vx + vy * vy + vz * vz + vw * vw);
        const float tn = sqrtf(t2);
        const float ts = fmaxf(tn, EPS_C);
        const float ct = cosf(tn);
        const float st = sinf(tn) / ts;
        px = ct * px + st * vx;
        py = ct * py + st * vy;
        pz = ct * pz + st * vz;
        pw = ct * pw + st * vw;
        pp = wsum64(px * px + py * py + pz * pz + pw * pw);
    }

    // output: (B, D) — wave 0 writes its replicated copy of p
    if (w == 0)
        *(float4*)(out + (size_t)b * DD + lane4) =
            make_float4(px, py, pz, pw);
}

extern "C" void kernel_launch(void* const* d_in, const int* in_sizes, int n_in,
                              void* d_out, int out_size, void* d_ws, size_t ws_size,
                              hipStream_t stream) {
    const float* points = (const float*)d_in[0];
    const float* weights = (const float*)d_in[1];
    float* out = (float*)d_out;
    (void)in_sizes; (void)n_in; (void)out_size; (void)d_ws; (void)ws_size;
    hipLaunchKernelGGL(frechet_mean_kernel, dim3(BB), dim3(THREADS), 0, stream,
                       points, weights, out);
}

// Round 4
// 670.955 us; speedup vs baseline: 1.0472x; 1.0472x over previous
//
#include <hip/hip_runtime.h>
#include <math.h>

// Problem constants (from reference setup_inputs)
#define BB 256
#define NN 1024
#define DD 256
#define NWAVES 16
#define THREADS 1024
#define PPW 64                    // points per wave
#define CPW 8                     // LDS-cached points per wave (balanced)
#define CACHEP (NWAVES * CPW)     // 128 cached points = 128 KB
#define N_ITERS_C 10
#define LR_C 0.5f
#define EPS_C 1e-7f

__device__ __forceinline__ float wsum64(float v) {
    #pragma unroll
    for (int off = 32; off; off >>= 1) v += __shfl_xor(v, off, 64);
    return v;
}

// theta = acos(c) via pi/2 - asin(c), Taylor through c^11 (error < 3e-6 at
// |c|=0.5; measured data has |c| <~ 0.31). Wave-uniform fallback keeps
// correctness for arbitrary c. c must already be clipped to [-1,1].
__device__ __forceinline__ float theta_from_cos(float c) {
    if (__builtin_expect(fabsf(c) > 0.5f, 0)) return acosf(c);
    const float c2 = c * c;
    float p = fmaf(c2, 0.022372159f, 0.030381944f);   // 945/42240, 105/3456
    p = fmaf(c2, p, 0.044642857f);                    // 15/336
    p = fmaf(c2, p, 0.075f);                          // 3/40
    p = fmaf(c2, p, 0.16666667f);                     // 1/6
    p = fmaf(c2, p, 1.0f);
    return fmaf(-c, p, 1.57079632679f);
}

// One workgroup per batch b; 16 waves x 64 lanes. Lane l owns dims [4l,4l+4)
// of D=256; every wave holds a replicated copy of the mean p in registers.
// Each wave processes 64 points/pass: 8 from LDS cache (balanced across all
// waves -> no barrier stragglers; gives compute to hide first prefetches),
// 56 streamed from global with a depth-2-pair software pipeline.
// LDS: 128KB cache + 16KB waveAcc + 4KB weights + 64B = ~148 KB, 1 block/CU.
__global__ __launch_bounds__(THREADS, 1)
void frechet_mean_kernel(const float* __restrict__ points,
                         const float* __restrict__ weights,
                         float* __restrict__ out) {
    const int b = blockIdx.x;
    const int w = threadIdx.x >> 6;
    const int lane = threadIdx.x & 63;
    const int lane4 = lane * 4;

    __shared__ float cacheQ[CACHEP][DD];   // 128 KB
    __shared__ float waveAcc[NWAVES][DD];  // 16 KB
    __shared__ float wLds[NN];             // 4 KB
    __shared__ float waveS[NWAVES];

    const float* __restrict__ Qb = points + (size_t)b * NN * DD;
    const float* __restrict__ Wb = weights + (size_t)b * NN;
    const float* rowBase = Qb + (size_t)(w * PPW) * DD + lane4;

    wLds[threadIdx.x] = Wb[threadIdx.x];
    __syncthreads();

    // ---- init pass: acc = sum_n w_n q_n ; fill LDS cache with j<CPW ----
    float ax = 0.f, ay = 0.f, az = 0.f, aww = 0.f, swt = 0.f;
    #pragma unroll
    for (int j = 0; j < CPW; ++j) {
        const float4 q = *(const float4*)(rowBase + (size_t)j * DD);
        *(float4*)(&cacheQ[w * CPW + j][lane4]) = q;
        const float wt = wLds[w * PPW + j];
        ax = fmaf(wt, q.x, ax); ay = fmaf(wt, q.y, ay);
        az = fmaf(wt, q.z, az); aww = fmaf(wt, q.w, aww);
        swt += wt;
    }
    #pragma unroll 4
    for (int j = CPW; j < PPW; ++j) {
        const float4 q = *(const float4*)(rowBase + (size_t)j * DD);
        const float wt = wLds[w * PPW + j];
        ax = fmaf(wt, q.x, ax); ay = fmaf(wt, q.y, ay);
        az = fmaf(wt, q.z, az); aww = fmaf(wt, q.w, aww);
        swt += wt;
    }
    *(float4*)(&waveAcc[w][lane4]) = make_float4(ax, ay, az, aww);
    if (lane == 0) waveS[w] = swt;
    __syncthreads();

    float gx = 0.f, gy = 0.f, gz = 0.f, gw = 0.f, wsumTot = 0.f;
    #pragma unroll
    for (int j = 0; j < NWAVES; ++j) {
        const float4 t = *(const float4*)(&waveAcc[j][lane4]);
        gx += t.x; gy += t.y; gz += t.z; gw += t.w;
        wsumTot += waveS[j];
    }
    const float wsumInv = 1.0f / wsumTot;
    gx *= wsumInv; gy *= wsumInv; gz *= wsumInv; gw *= wsumInv;

    const float nrm2 = wsum64(gx * gx + gy * gy + gz * gz + gw * gw);
    const float rn = 1.0f / fmaxf(sqrtf(nrm2), EPS_C);
    float px = gx * rn, py = gy * rn, pz = gz * rn, pw = gw * rn;
    float pp = wsum64(px * px + py * py + pz * pz + pw * pw);  // ||p||^2

    const float CLIP = 1.0f - 1e-7f;

    for (int it = 0; it < N_ITERS_C; ++it) {
        __syncthreads();  // previous waveAcc reads done before rewrite
        float accx = 0.f, accy = 0.f, accz = 0.f, accw = 0.f, s = 0.f;

        // Two points per call, shuffle chains interleaved (2-deep ILP).
        // ||u||^2 = 1 - 2 cos <p,q> + cos^2 ||p||^2 (||q||==1 analytically).
        auto process2 = [&](const float4 q0, const float wc0,
                            const float4 q1, const float wc1) {
            float d0 = fmaf(q0.x, px, fmaf(q0.y, py, fmaf(q0.z, pz, q0.w * pw)));
            float d1 = fmaf(q1.x, px, fmaf(q1.y, py, fmaf(q1.z, pz, q1.w * pw)));
            #pragma unroll
            for (int off = 32; off; off >>= 1) {
                d0 += __shfl_xor(d0, off, 64);
                d1 += __shfl_xor(d1, off, 64);
            }
            const float c0v = fminf(fmaxf(d0, -CLIP), CLIP);
            const float c1v = fminf(fmaxf(d1, -CLIP), CLIP);
            const float th0 = theta_from_cos(c0v);
            const float th1 = theta_from_cos(c1v);
            float u0 = fmaf(c0v * c0v, pp, fmaf(-2.0f * c0v, d0, 1.0f));
            float u1 = fmaf(c1v * c1v, pp, fmaf(-2.0f * c1v, d1, 1.0f));
            const float c0 = wc0 * th0 * rsqrtf(fmaxf(u0, 1e-14f));
            const float c1 = wc1 * th1 * rsqrtf(fmaxf(u1, 1e-14f));
            accx = fmaf(c0, q0.x, fmaf(c1, q1.x, accx));
            accy = fmaf(c0, q0.y, fmaf(c1, q1.y, accy));
            accz = fmaf(c0, q0.z, fmaf(c1, q1.z, accz));
            accw = fmaf(c0, q0.w, fmaf(c1, q1.w, accw));
            s = fmaf(c0, c0v, fmaf(c1, c1v, s));
        };

        // prefetch first two global pairs (points 8..11)
        float4 a0 = *(const float4*)(rowBase + (size_t)8 * DD);
        float4 a1 = *(const float4*)(rowBase + (size_t)9 * DD);
        float4 b0 = *(const float4*)(rowBase + (size_t)10 * DD);
        float4 b1 = *(const float4*)(rowBase + (size_t)11 * DD);

        // LDS head: 8 cached points — compute cover for the prefetches
        #pragma unroll
        for (int j = 0; j < CPW; j += 2) {
            const float4 q0 = *(const float4*)(&cacheQ[w * CPW + j][lane4]);
            const float4 q1 = *(const float4*)(&cacheQ[w * CPW + j + 1][lane4]);
            process2(q0, wLds[w * PPW + j], q1, wLds[w * PPW + j + 1]);
        }

        // pipelined main stream: process pair j, prefetch pair j+4
        #pragma unroll 2
        for (int j = CPW; j < PPW - 4; j += 2) {
            const float4 n0 = *(const float4*)(rowBase + (size_t)(j + 4) * DD);
            const float4 n1 = *(const float4*)(rowBase + (size_t)(j + 5) * DD);
            process2(a0, wLds[w * PPW + j], a1, wLds[w * PPW + j + 1]);
            a0 = b0; a1 = b1; b0 = n0; b1 = n1;
        }
        process2(a0, wLds[w * PPW + PPW - 4], a1, wLds[w * PPW + PPW - 3]);
        process2(b0, wLds[w * PPW + PPW - 2], b1, wLds[w * PPW + PPW - 1]);

        *(float4*)(&waveAcc[w][lane4]) = make_float4(accx, accy, accz, accw);
        if (lane == 0) waveS[w] = s;
        __syncthreads();

        float grx = 0.f, gry = 0.f, grz = 0.f, grw = 0.f, sTot = 0.f;
        #pragma unroll
        for (int j = 0; j < NWAVES; ++j) {
            const float4 t = *(const float4*)(&waveAcc[j][lane4]);
            grx += t.x; gry += t.y; grz += t.z; grw += t.w;
            sTot += waveS[j];
        }
        // v = LR * wsumInv * (gr - sTot * p)
        const float scale = LR_C * wsumInv;
        const float vx = scale * (grx - sTot * px);
        const float vy = scale * (gry - sTot * py);
        const float vz = scale * (grz - sTot * pz);
        const float vw = scale * (grw - sTot * pw);

        const float t2 = wsum64(vx * vx + vy * vy + vz * vz + vw * vw);
        const float tn = sqrtf(t2);
        const float ts = fmaxf(tn, EPS_C);
        const float ct = cosf(tn);
        const float st = sinf(tn) / ts;
        px = ct * px + st * vx;
        py = ct * py + st * vy;
        pz = ct * pz + st * vz;
        pw = ct * pw + st * vw;
        pp = wsum64(px * px + py * py + pz * pz + pw * pw);
    }

    if (w == 0)
        *(float4*)(out + (size_t)b * DD + lane4) =
            make_float4(px, py, pz, pw);
}

extern "C" void kernel_launch(void* const* d_in, const int* in_sizes, int n_in,
                              void* d_out, int out_size, void* d_ws, size_t ws_size,
                              hipStream_t stream) {
    const float* points = (const float*)d_in[0];
    const float* weights = (const float*)d_in[1];
    float* out = (float*)d_out;
    (void)in_sizes; (void)n_in; (void)out_size; (void)d_ws; (void)ws_size;
    hipLaunchKernelGGL(frechet_mean_kernel, dim3(BB), dim3(THREADS), 0, stream,
                       points, weights, out);
}